// Round 19
// baseline (122.607 us; speedup 1.0000x reference)
//
#include <hip/hip_runtime.h>
#include <math.h>

#define NB 4
#define CC 256
#define CO 32
#define NN 4096
#define MU 320   // concat projection rows: 32 q + 32 k + 256 v
#define LOG2E 1.44269504088896f

typedef __attribute__((ext_vector_type(4))) float f4;
typedef __attribute__((ext_vector_type(8))) short s8;          // 8 bf16 MFMA frag
typedef __attribute__((ext_vector_type(8))) unsigned short us8;
typedef __attribute__((ext_vector_type(2))) unsigned int u2;
typedef __attribute__((ext_vector_type(4))) unsigned int u4i;

// fp32 -> bf16 (RNE), scalar fallback
__device__ __forceinline__ unsigned short f2bf(float f) {
    unsigned int u = __float_as_uint(f);
    u = (u + 0x7FFFu + ((u >> 16) & 1u)) >> 16;
    return (unsigned short)u;
}
// HW packed convert: dst = {bf16(lo), bf16(hi)}
__device__ __forceinline__ unsigned int cvtpk(float lo, float hi) {
    unsigned int r;
    asm("v_cvt_pk_bf16_f32 %0, %1, %2" : "=v"(r) : "v"(lo), "v"(hi));
    return r;
}
// XOR-swizzled byte offset within a 128B-row LDS tile (verified round 8)
__device__ __forceinline__ int swz128(int row, int colByte) {
    return row * 128 + (colByte ^ ((row & 7) << 4));
}
// Barrier draining only LDS ops; global prefetch loads stay in flight.
#define LDS_BARRIER() asm volatile("s_waitcnt lgkmcnt(0)\n\ts_barrier" ::: "memory")

union s8u4 { s8 s; u4i u; };

// ---------------------------------------------------------------------------
// prepw: grid 80. Wb[320][256] bf16, fb[320] f32.  (passing, unchanged)
// ---------------------------------------------------------------------------
__global__ __launch_bounds__(256) void prepw_kernel(
    const float* __restrict__ Wq, const float* __restrict__ bq,
    const float* __restrict__ Wk, const float* __restrict__ bk,
    const float* __restrict__ Wv, const float* __restrict__ bv,
    unsigned short* __restrict__ Wb, float* __restrict__ fb)
{
    const int t = threadIdx.x;
    #pragma unroll
    for (int i = 0; i < 4; ++i) {
        const int e = blockIdx.x * 1024 + i * 256 + t;
        const int u = e >> 8, c = e & 255;
        float val = (u < 32) ? Wq[u * 256 + c]
                  : (u < 64) ? Wk[(u - 32) * 256 + c]
                             : Wv[(u - 64) * 256 + c];
        Wb[e] = f2bf(val);
    }
    if (blockIdx.x == 0) {
        for (int u = t; u < MU; u += 256)
            fb[u] = (u < 32) ? bq[u] : (u < 64) ? bk[u - 32] : bv[u - 64];
    }
}

// ---------------------------------------------------------------------------
// projf: fused transpose + MFMA projection (passing, unchanged).
// ---------------------------------------------------------------------------
__global__ __launch_bounds__(256) void projf_kernel(
    const float* __restrict__ x, const unsigned short* __restrict__ Wb,
    const float* __restrict__ fb,
    unsigned short* __restrict__ qb, unsigned short* __restrict__ kb,
    unsigned short* __restrict__ vtb)
{
    __shared__ float xl[32][260];

    const int t   = threadIdx.x;
    const int b   = blockIdx.x >> 7;
    const int nbl = blockIdx.x & 127;
    const int n0  = nbl * 32;

    {
        const int nl = t & 7;
        const int c8 = t >> 3;
        #pragma unroll
        for (int pass = 0; pass < 8; ++pass) {
            const int c = c8 + pass * 32;
            f4 xv = *reinterpret_cast<const f4*>(x + ((size_t)(b * CC + c)) * NN + n0 + nl * 4);
            #pragma unroll
            for (int j = 0; j < 4; ++j) xl[nl * 4 + j][c] = xv[j];
        }
    }
    __syncthreads();

    const int w    = t >> 6;
    const int l    = t & 63;
    const int l15  = l & 15;
    const int g4   = l >> 4;
    const int nw   = w & 1;
    const int uw   = w >> 1;
    const int nloc = nw * 16 + l15;
    const int n    = n0 + nloc;

    s8 bfr[8];
    #pragma unroll
    for (int kk = 0; kk < 8; ++kk) {
        f4 a  = *reinterpret_cast<const f4*>(&xl[nloc][kk * 32 + g4 * 8]);
        f4 c2 = *reinterpret_cast<const f4*>(&xl[nloc][kk * 32 + g4 * 8 + 4]);
        s8u4 tmp;
        tmp.u = (u4i){ cvtpk(a[0], a[1]), cvtpk(a[2], a[3]),
                       cvtpk(c2[0], c2[1]), cvtpk(c2[2], c2[3]) };
        bfr[kk] = tmp.s;
    }

    const f4 z = {0.f, 0.f, 0.f, 0.f};
    unsigned short* qrow = qb + ((size_t)(b * NN + n)) * CO;
    unsigned short* krow = kb + ((size_t)(b * NN + n)) * CO;

    #pragma unroll
    for (int i = 0; i < 10; ++i) {
        const int u0 = (uw * 10 + i) * 16;
        f4 acc = z;
        #pragma unroll
        for (int kk = 0; kk < 8; ++kk) {
            s8 af = *reinterpret_cast<const s8*>(Wb + (size_t)(u0 + l15) * CC + kk * 32 + g4 * 8);
            acc = __builtin_amdgcn_mfma_f32_16x16x32_bf16(af, bfr[kk], acc, 0, 0, 0);
        }
        f4 bias4 = *reinterpret_cast<const f4*>(fb + u0 + g4 * 4);
        if (u0 < 32) {
            u2 pw = { cvtpk((acc[0] + bias4[0]) * LOG2E, (acc[1] + bias4[1]) * LOG2E),
                      cvtpk((acc[2] + bias4[2]) * LOG2E, (acc[3] + bias4[3]) * LOG2E) };
            *reinterpret_cast<u2*>(qrow + u0 + g4 * 4) = pw;
        } else if (u0 < 64) {
            u2 pw = { cvtpk(acc[0] + bias4[0], acc[1] + bias4[1]),
                      cvtpk(acc[2] + bias4[2], acc[3] + bias4[3]) };
            *reinterpret_cast<u2*>(krow + (u0 - 32) + g4 * 4) = pw;
        } else {
            const int cbase = u0 - 64 + g4 * 4;
            #pragma unroll
            for (int r = 0; r < 4; ++r)
                vtb[((size_t)(b * CC + cbase + r)) * NN + n] = f2bf(acc[r] + bias4[r]);
        }
    }
}

// ---------------------------------------------------------------------------
// colstats: civ + scaled V in MFMA B-fragment order (vfr). (passing, unchanged)
// ---------------------------------------------------------------------------
__global__ __launch_bounds__(256) void colstats_kernel(
    const unsigned short* __restrict__ qb, const unsigned short* __restrict__ kb,
    const unsigned short* __restrict__ vtb, unsigned short* __restrict__ vfr)
{
    __shared__ float red[4][16];
    __shared__ float civl[16];

    const int t   = threadIdx.x;
    const int b   = blockIdx.x >> 8;
    const int mb  = blockIdx.x & 255;
    const int l   = t & 63;
    const int w   = t >> 6;
    const int l15 = l & 15;
    const int g4  = l >> 4;
    const int m   = mb * 16 + l15;

    const unsigned short* qbB = qb + (size_t)b * NN * CO;
    s8 kfrag = *reinterpret_cast<const s8*>(kb + ((size_t)b * NN + m) * CO + g4 * 8);

    const f4 z = {0.f, 0.f, 0.f, 0.f};
    float ssum = 0.f;

    const int nbeg = w * 1024, nend = nbeg + 1024;
    for (int n0 = nbeg; n0 < nend; n0 += 32) {
        s8 a0 = *reinterpret_cast<const s8*>(qbB + (size_t)(n0 + l15) * CO + g4 * 8);
        s8 a1 = *reinterpret_cast<const s8*>(qbB + (size_t)(n0 + 16 + l15) * CO + g4 * 8);
        f4 d0 = __builtin_amdgcn_mfma_f32_16x16x32_bf16(a0, kfrag, z, 0, 0, 0);
        f4 d1 = __builtin_amdgcn_mfma_f32_16x16x32_bf16(a1, kfrag, z, 0, 0, 0);
        #pragma unroll
        for (int r = 0; r < 4; ++r) ssum += exp2f(d0[r]) + exp2f(d1[r]);
    }

    ssum += __shfl_xor(ssum, 16);
    ssum += __shfl_xor(ssum, 32);
    if (l < 16) red[w][l15] = ssum;
    __syncthreads();
    if (w == 0 && l < 16)
        civl[l15] = 1.0f / (red[0][l15] + red[1][l15] + red[2][l15] + red[3][l15]);
    __syncthreads();

    const int mt   = mb >> 2;
    const int ksl  = (mb >> 1) & 1;
    const int g4b  = (mb & 1) * 2;
    const int cg   = t >> 4;
    const int l15v = t & 15;
    const unsigned short* vp = vtb + ((size_t)(b * CC + t)) * NN + mb * 16;
    unsigned short* dst = vfr + (size_t)b * 1048576
                        + (((mt * 16 + cg) * 2 + ksl) << 9)
                        + (g4b * 16 + l15v) * 8;
    #pragma unroll
    for (int i = 0; i < 2; ++i) {
        us8 vv = *reinterpret_cast<const us8*>(vp + i * 8);
        u4i o;
        #pragma unroll
        for (int e2 = 0; e2 < 4; ++e2) {
            float f0 = __uint_as_float((unsigned int)vv[2 * e2]     << 16) * civl[i * 8 + 2 * e2];
            float f1 = __uint_as_float((unsigned int)vv[2 * e2 + 1] << 16) * civl[i * 8 + 2 * e2 + 1];
            o[e2] = cvtpk(f0, f1);
        }
        *reinterpret_cast<u4i*>(dst + i * 128) = o;
    }
}

// ---------------------------------------------------------------------------
// attn: V staged into LDS from vfr (coalesced 32B/thread, linear LDS layout,
// conflict-free b128 reads), P in swizzled LDS.  TWO-TILE-DEEP register
// prefetch (A/B sets) + lgkmcnt-only barriers: at every barrier the in-flight
// global loads are for tile i+3/i+4, consumed one barrier later.
// 64n x 128c, 512 thr / 8 waves, grid 512 (2 blocks/CU, 48 KB LDS).
// ---------------------------------------------------------------------------
__global__ __launch_bounds__(512) void attn_kernel(
    const unsigned short* __restrict__ qb, const unsigned short* __restrict__ kb,
    const unsigned short* __restrict__ vfr, float* __restrict__ out)
{
    __shared__ __align__(16) char plds[2][64 * 128];    // P tile [n][m] bf16, swizzled
    __shared__ __align__(16) char vlds[2][16384];       // V' tile, linear vfr order

    const int t    = threadIdx.x;
    const int bid  = blockIdx.x;
    const int cblk = bid & 1;
    const int nblk = (bid >> 1) & 63;
    const int b    = bid >> 7;
    const int n0   = nblk * 64;
    const int c0   = cblk * 128;
    const int l    = t & 63;
    const int w    = t >> 6;        // 0..7
    const int l15  = l & 15;
    const int g4   = l >> 4;
    const int g    = w >> 1;        // S n-group (16 rows)
    const int p    = w & 1;         // S j-pair
    const int wrn  = w >> 2;        // PV n-half
    const int wcq  = w & 3;         // PV c-quarter

    const unsigned short* qbB = qb  + (size_t)b * NN * CO;
    const unsigned short* kbB = kb  + (size_t)b * NN * CO;

    // wave's 16 S-rows (B-operand of swapped MFMA)
    s8 qfrag = *reinterpret_cast<const s8*>(qbB + (size_t)(n0 + g * 16 + l15) * CO + g4 * 8);

    // ---- loop-invariant LDS byte offsets ----
    const int pw0  = swz128(g * 16 + l15, (2 * p) * 32 + g4 * 8);
    const int pw1  = swz128(g * 16 + l15, (2 * p + 1) * 32 + g4 * 8);
    const int prk0a0 = swz128(wrn * 32 +      l15,      g4 * 16);
    const int prk0a1 = swz128(wrn * 32 + 16 + l15,      g4 * 16);
    const int prk1a0 = swz128(wrn * 32 +      l15, 64 + g4 * 16);
    const int prk1a1 = swz128(wrn * 32 + 16 + l15, 64 + g4 * 16);
    const int vw0 = t * 16;                 // V stage writes (linear, conflict-free)
    const int vw1 = 8192 + t * 16;
    const int vrb = wcq * 4096 + l * 16;    // V read base: cg-pair of this c-quarter

    // ---- 2-deep incremental global pointers (A = even tiles, B = odd) ----
    const unsigned short* kpA = kbB + (size_t)((2 * p) * 16 + l15) * CO + g4 * 8;
    const unsigned short* kpB = kpA + (size_t)64 * CO;
    // vfr tile stride = 16384 ushorts; block c-half at chunk base (c0>>4)*2*512
    const unsigned short* vpA = vfr + (size_t)b * 1048576 + (size_t)(c0 >> 4) * 1024 + t * 8;
    const unsigned short* vpB = vpA + 16384;

    s8 kA0, kA1, kB0, kB1;
    s8 vA0, vA1, vB0, vB1;
    const f4 z = {0.f, 0.f, 0.f, 0.f};

#define LOADA() do { \
        kA0 = *reinterpret_cast<const s8*>(kpA); \
        kA1 = *reinterpret_cast<const s8*>(kpA + 16 * CO); \
        vA0 = *reinterpret_cast<const s8*>(vpA); \
        vA1 = *reinterpret_cast<const s8*>(vpA + 4096); \
        kpA += 128 * CO; vpA += 32768; \
    } while (0)

#define LOADB() do { \
        kB0 = *reinterpret_cast<const s8*>(kpB); \
        kB1 = *reinterpret_cast<const s8*>(kpB + 16 * CO); \
        vB0 = *reinterpret_cast<const s8*>(vpB); \
        vB1 = *reinterpret_cast<const s8*>(vpB + 4096); \
        kpB += 128 * CO; vpB += 32768; \
    } while (0)

#define STAGE(BUF, K0, K1, V0, V1) do { \
        f4 d0 = __builtin_amdgcn_mfma_f32_16x16x32_bf16(K0, qfrag, z, 0, 0, 0); \
        f4 d1 = __builtin_amdgcn_mfma_f32_16x16x32_bf16(K1, qfrag, z, 0, 0, 0); \
        u2 pq0 = { cvtpk(exp2f(d0[0]), exp2f(d0[1])), cvtpk(exp2f(d0[2]), exp2f(d0[3])) }; \
        u2 pq1 = { cvtpk(exp2f(d1[0]), exp2f(d1[1])), cvtpk(exp2f(d1[2]), exp2f(d1[3])) }; \
        *reinterpret_cast<u2*>(plds[BUF] + pw0) = pq0; \
        *reinterpret_cast<u2*>(plds[BUF] + pw1) = pq1; \
        *reinterpret_cast<s8*>(vlds[BUF] + vw0) = V0; \
        *reinterpret_cast<s8*>(vlds[BUF] + vw1) = V1; \
    } while (0)

#define PVSTEP(BUF) do { \
        s8 pa00 = *reinterpret_cast<const s8*>(plds[BUF] + prk0a0); \
        s8 pa01 = *reinterpret_cast<const s8*>(plds[BUF] + prk0a1); \
        s8 pa10 = *reinterpret_cast<const s8*>(plds[BUF] + prk1a0); \
        s8 pa11 = *reinterpret_cast<const s8*>(plds[BUF] + prk1a1); \
        s8 vb00 = *reinterpret_cast<const s8*>(vlds[BUF] + vrb); \
        s8 vb10 = *reinterpret_cast<const s8*>(vlds[BUF] + vrb + 1024); \
        s8 vb01 = *reinterpret_cast<const s8*>(vlds[BUF] + vrb + 2048); \
        s8 vb11 = *reinterpret_cast<const s8*>(vlds[BUF] + vrb + 3072); \
        __builtin_amdgcn_s_setprio(1); \
        acc[0][0] = __builtin_amdgcn_mfma_f32_16x16x32_bf16(pa00, vb00, acc[0][0], 0, 0, 0); \
        acc[0][1] = __builtin_amdgcn_mfma_f32_16x16x32_bf16(pa00, vb01, acc[0][1], 0, 0, 0); \
        acc[1][0] = __builtin_amdgcn_mfma_f32_16x16x32_bf16(pa01, vb00, acc[1][0], 0, 0, 0); \
        acc[1][1] = __builtin_amdgcn_mfma_f32_16x16x32_bf16(pa01, vb01, acc[1][1], 0, 0, 0); \
        acc[0][0] = __builtin_amdgcn_mfma_f32_16x16x32_bf16(pa10, vb10, acc[0][0], 0, 0, 0); \
        acc[0][1] = __builtin_amdgcn_mfma_f32_16x16x32_bf16(pa10, vb11, acc[0][1], 0, 0, 0); \
        acc[1][0] = __builtin_amdgcn_mfma_f32_16x16x32_bf16(pa11, vb10, acc[1][0], 0, 0, 0); \
        acc[1][1] = __builtin_amdgcn_mfma_f32_16x16x32_bf16(pa11, vb11, acc[1][1], 0, 0, 0); \
        __builtin_amdgcn_s_setprio(0); \
    } while (0)

    f4 acc[2][2];
    acc[0][0] = z; acc[0][1] = z; acc[1][0] = z; acc[1][1] = z;

    // prologue: load tiles 0,1; stage tile 0; load tile 2
    LOADA();                         // tile 0
    LOADB();                         // tile 1
    STAGE(0, kA0, kA1, vA0, vA1);    // stage tile 0
    LOADA();                         // tile 2
    LDS_BARRIER();

    for (int i = 0; i < 64; i += 2) {
        // buf0 = tile i (staged).  B set = tile i+1, A set = tile i+2.
        STAGE(1, kB0, kB1, vB0, vB1);           // stage tile i+1
        if (i + 3 < 64) LOADB();                // load tile i+3
        PVSTEP(0);                              // compute tile i
        LDS_BARRIER();

        if (i + 2 < 64) STAGE(0, kA0, kA1, vA0, vA1);   // stage tile i+2
        if (i + 4 < 64) LOADA();                        // load tile i+4
        PVSTEP(1);                              // compute tile i+1
        LDS_BARRIER();
    }

#undef LOADA
#undef LOADB
#undef STAGE
#undef PVSTEP

    // D layout: col = lane&15 (c), row = g4*4 + r (n)
    #pragma unroll
    for (int a = 0; a < 2; ++a) {
        const int row = n0 + wrn * 32 + a * 16 + g4 * 4;
        #pragma unroll
        for (int c = 0; c < 2; ++c) {
            const int col = c0 + wcq * 32 + c * 16 + l15;
            #pragma unroll
            for (int r = 0; r < 4; ++r)
                out[((size_t)(b * NN + row + r)) * CC + col] = acc[a][c][r];
        }
    }
}

extern "C" void kernel_launch(void* const* d_in, const int* in_sizes, int n_in,
                              void* d_out, int out_size, void* d_ws, size_t ws_size,
                              hipStream_t stream)
{
    const float* x  = (const float*)d_in[0];
    const float* Wq = (const float*)d_in[1];
    const float* bq = (const float*)d_in[2];
    const float* Wk = (const float*)d_in[3];
    const float* bk = (const float*)d_in[4];
    const float* Wv = (const float*)d_in[5];
    const float* bv = (const float*)d_in[6];
    float* out = (float*)d_out;

    // ws layout: qb(1MB) | kb(1MB) | vtb(8MB) | vfr(8MB) | Wb(160KB) | fb
    unsigned short* qb  = (unsigned short*)d_ws;
    unsigned short* kb  = qb  + (size_t)NB * NN * CO;
    unsigned short* vtb = kb  + (size_t)NB * NN * CO;
    unsigned short* vfr = vtb + (size_t)NB * CC * NN;
    unsigned short* Wb  = vfr + (size_t)NB * CC * NN;
    float*          fb  = (float*)(Wb + (size_t)MU * CC);

    prepw_kernel<<<dim3(80), dim3(256), 0, stream>>>(Wq, bq, Wk, bk, Wv, bv, Wb, fb);
    projf_kernel<<<dim3(512), dim3(256), 0, stream>>>(x, Wb, fb, qb, kb, vtb);
    colstats_kernel<<<dim3(1024), dim3(256), 0, stream>>>(qb, kb, vtb, vfr);
    attn_kernel<<<dim3(512), dim3(512), 0, stream>>>(qb, kb, vfr, out);
}